// Round 7
// baseline (43.871 us; speedup 1.0000x reference)
//
#include <hip/hip_runtime.h>
#include <math.h>

#define HW    524288u     // 512*1024 (= 2^19)
#define NPIX  2097152u    // 4*512*1024
#define NCH   19
#define NC    12
#define BLK   256
#define GRID  512         // 4096 px/block: 8 iters x 2 px/thread (float2)
#define BLK2  512         // pass2: one thread per pass1 block-slot

typedef float f32x2 __attribute__((ext_vector_type(2)));

// ---- per-pixel: 19 logits -> (sum of 12 plane values squared, argmax plane)
__device__ __forceinline__ void pixel_eval(const float p[NCH], float& s2, int& pred) {
    float o[NC];
    o[2] = p[2] + p[3] + p[4];
    o[4] = p[6] + p[7];
    o[5] = p[8] + p[9] + p[10];
    o[8] = p[13] + p[14] + p[15];
    float Z = 0.f;
    #pragma unroll
    for (int c = 0; c < NCH; ++c) {
        float t = __expf(p[c]);          // inputs ~N(0,1): f32 expf safe without max-subtract
        Z += t;
        if (c == 0)  o[0]  = t;
        if (c == 1)  o[1]  = t;
        if (c == 5)  o[3]  = t;
        if (c == 11) o[6]  = t;
        if (c == 12) o[7]  = t;
        if (c == 16) o[9]  = t;
        if (c == 17) o[10] = t;
        if (c == 18) o[11] = t;
    }
    float invZ = __builtin_amdgcn_rcpf(Z);
    o[0] *= invZ; o[1] *= invZ; o[3]  *= invZ; o[6]  *= invZ;
    o[7] *= invZ; o[9] *= invZ; o[10] *= invZ; o[11] *= invZ;

    float best = o[0]; int bi = 0; float acc = o[0] * o[0];
    #pragma unroll
    for (int k = 1; k < NC; ++k) {
        acc = fmaf(o[k], o[k], acc);
        if (o[k] > best) { best = o[k]; bi = k; }  // strict > == jnp.argmax first-max
    }
    s2 = acc; pred = bi;
}

// issue 19 channel loads for iteration IT into BUF (asm: compiler can't insert waits
// or shrink the in-flight buffer - this is what fixed the R5 MLP collapse)
#define ISSUE(BUF, IT)                                                          \
    _Pragma("unroll")                                                           \
    for (int c = 0; c < NCH; ++c) {                                             \
        unsigned vo = voff0 + (IT) * 2048u + (unsigned)c * 0x200000u;           \
        asm volatile("global_load_dwordx2 %0, %1, %2"                           \
                     : "=v"(BUF[c]) : "v"(vo), "s"(sbase));                     \
    }

#define WAITCNT(N)                                                              \
    asm volatile("s_waitcnt vmcnt(" #N ")");                                    \
    __builtin_amdgcn_sched_barrier(0);   /* rule #18 */

#define CONSUME(BUF)                                                            \
    _Pragma("unroll")                                                           \
    for (int j = 0; j < 2; ++j) {                                               \
        float pv[NCH];                                                          \
        _Pragma("unroll")                                                       \
        for (int c = 0; c < NCH; ++c) pv[c] = j ? BUF[c].y : BUF[c].x;          \
        float s2; int pred;                                                     \
        pixel_eval(pv, s2, pred);                                               \
        _Pragma("unroll")                                                       \
        for (int k = 0; k < NC; ++k) {                                          \
            bool h = (pred == k);                                               \
            cnt_i[k] += (int)__popcll(__ballot(h));  /* wave-uniform SALU acc */ \
            sum[k] += h ? s2 : 0.f;                                             \
        }                                                                       \
    }

__global__ __launch_bounds__(BLK, 2) void msiwc_pass1(const float* __restrict__ x,
                                                      float* __restrict__ ws) {
    float sum[NC];
    int cnt_i[NC];
    #pragma unroll
    for (int k = 0; k < NC; ++k) { sum[k] = 0.f; cnt_i[k] = 0; }

    // block owns 4096 contiguous pixels, all in one batch (2^19 % 4096 == 0)
    unsigned px0 = blockIdx.x * 4096u;
    unsigned n   = px0 >> 19;
    unsigned hw0 = px0 & (HW - 1u);
    const float* sbase = x + (size_t)n * NCH * HW;     // uniform -> SGPR pair
    unsigned voff0 = (hw0 + threadIdx.x * 2u) * 4u;    // per-lane byte offset

    f32x2 va[NCH], vb[NCH];                            // double buffer, 76 VGPRs

    // 8-deep hand pipeline, counted vmcnt (T4): never drain to 0 in steady state
    ISSUE(va, 0);
    ISSUE(vb, 1); WAITCNT(19); CONSUME(va);
    ISSUE(va, 2); WAITCNT(19); CONSUME(vb);
    ISSUE(vb, 3); WAITCNT(19); CONSUME(va);
    ISSUE(va, 4); WAITCNT(19); CONSUME(vb);
    ISSUE(vb, 5); WAITCNT(19); CONSUME(va);
    ISSUE(va, 6); WAITCNT(19); CONSUME(vb);
    ISSUE(vb, 7); WAITCNT(19); CONSUME(va);
    WAITCNT(0);   CONSUME(vb);

    // butterfly only the sums (cnt is already wave-uniform in SGPRs)
    #pragma unroll
    for (int k = 0; k < NC; ++k) {
        #pragma unroll
        for (int off = 32; off > 0; off >>= 1)
            sum[k] += __shfl_xor(sum[k], off, 64);
    }

    // lane l in [0,12) selects class-l values via cndmask chain (compile-time regs)
    unsigned lane = threadIdx.x & 63u, wid = threadIdx.x >> 6;
    float sval = sum[0];
    float cval = (float)cnt_i[0];
    #pragma unroll
    for (int k = 1; k < NC; ++k) {
        bool sel = (lane == (unsigned)k);
        sval = sel ? sum[k]          : sval;
        cval = sel ? (float)cnt_i[k] : cval;
    }

    __shared__ float s_red[BLK / 64][2 * NC];
    if (lane < NC) { s_red[wid][lane] = cval; s_red[wid][NC + lane] = sval; }
    __syncthreads();

    // per-block partial slot: ws[block][0..11]=cnt, [12..23]=sum. No atomics,
    // no memset (every slot written every call -> deterministic).
    if (threadIdx.x < 2 * NC) {
        float a = 0.f;
        #pragma unroll
        for (int w = 0; w < BLK / 64; ++w) a += s_red[w][threadIdx.x];
        ws[blockIdx.x * 2 * NC + threadIdx.x] = a;
    }
}

// ---- pass 2: reduce 512 block-slots, compute weights + final scalar
__global__ __launch_bounds__(BLK2) void msiwc_pass2(const float* __restrict__ ws,
                                                    float* __restrict__ out) {
    // thread t reads slot t (24 floats), per-class registers
    float v[2 * NC];
    const float* row = ws + threadIdx.x * 2 * NC;
    #pragma unroll
    for (int k = 0; k < 2 * NC; ++k) v[k] = row[k];

    #pragma unroll
    for (int k = 0; k < 2 * NC; ++k) {
        #pragma unroll
        for (int off = 32; off > 0; off >>= 1)
            v[k] += __shfl_xor(v[k], off, 64);
    }

    __shared__ float s_red[BLK2 / 64][2 * NC];
    unsigned lane = threadIdx.x & 63u, wid = threadIdx.x >> 6;
    if (lane == 0) {
        #pragma unroll
        for (int k = 0; k < 2 * NC; ++k) s_red[wid][k] = v[k];
    }
    __syncthreads();

    if (threadIdx.x == 0) {
        double tot = 0.0;
        #pragma unroll
        for (int k = 0; k < NC; ++k) {
            double h = 0.0, s = 0.0;
            #pragma unroll
            for (int w = 0; w < BLK2 / 64; ++w) { h += s_red[w][k]; s += s_red[w][NC + k]; }
            double wgt = pow(h, 0.2) * pow((double)NPIX, 0.8);
            if (wgt < 1.0) wgt = 1.0;
            tot += s / wgt;
        }
        out[0] = (float)(-tot / 48.0);   // N*C = 4*12
    }
}

extern "C" void kernel_launch(void* const* d_in, const int* in_sizes, int n_in,
                              void* d_out, int out_size, void* d_ws, size_t ws_size,
                              hipStream_t stream) {
    const float* x = (const float*)d_in[0];
    float* ws = (float*)d_ws;

    msiwc_pass1<<<GRID, BLK, 0, stream>>>(x, ws);
    msiwc_pass2<<<1, BLK2, 0, stream>>>(ws, (float*)d_out);
}